// Round 4
// baseline (396.387 us; speedup 1.0000x reference)
//
#include <hip/hip_runtime.h>
#include <hip/hip_bf16.h>

// MDN NLL, fully fused. N=524288 Dx=128 Dt=64 M=32 K=8.
// Memory-bound target: 470 MB reads -> ~75us floor at 6.3 TB/s.
// R4 design: NO DMA, no vmcnt drains. x reg-staged -> bf16 LDS (8 KB, single
// buffer, lgkm-only barriers). t/y direct from global (L1/L2-served
// redundancy). Gate logits via MFMA with t-fragments built pre-barrier.
// R2 lesson: (512,4) -> 64-VGPR cap -> spill disaster.
// R3 lesson: VGPR 128 + AGPR overflow -> 1 block/CU -> latency-bound.

#define NN 524288
#define DX 128
#define DT 64
#define MDIM 32
#define KEXP 8
#define TILE_R 32
#define THREADS 512
#define GRID_MAIN 512
#define TILES_TOTAL (NN / TILE_R)        // 16384
#define TPB (TILES_TOTAL / GRID_MAIN)    // 32

typedef __bf16 bf16x8 __attribute__((ext_vector_type(8)));
typedef float f32x4 __attribute__((ext_vector_type(4)));

__device__ __forceinline__ bf16x8 cvt8(const f32x4 a, const f32x4 b) {
  bf16x8 r;
  r[0] = (__bf16)a[0]; r[1] = (__bf16)a[1]; r[2] = (__bf16)a[2]; r[3] = (__bf16)a[3];
  r[4] = (__bf16)b[0]; r[5] = (__bf16)b[1]; r[6] = (__bf16)b[2]; r[7] = (__bf16)b[3];
  return r;
}

#define MFMA16(a, b, c) __builtin_amdgcn_mfma_f32_16x16x32_bf16(a, b, c, 0, 0, 0)

// LDS-only barrier: global loads stay in flight across it.
#define B_LDS() do { \
  asm volatile("s_waitcnt lgkmcnt(0)" ::: "memory"); \
  __builtin_amdgcn_s_barrier(); \
  __builtin_amdgcn_sched_barrier(0); } while (0)

__global__ __launch_bounds__(THREADS, 2) void mdn_main(
    const float* __restrict__ x, const float* __restrict__ t,
    const float* __restrict__ y, const float* __restrict__ Wm,
    const float* __restrict__ bm, const float* __restrict__ Wv,
    const float* __restrict__ bv, const float* __restrict__ Wg,
    const float* __restrict__ bg, float* __restrict__ partials,
    float* __restrict__ out_atomic)
{
  __shared__ __align__(16) unsigned short xs[TILE_R * DX];  // bf16 tile, 8 KB
  __shared__ float ll_s[TILE_R * 17];                       // padded [32][17]
  __shared__ float red_s[8];

  const int tid = threadIdx.x;
  const int lane = tid & 63;
  const int wv = tid >> 6;       // wave id == expert k
  const int l15 = lane & 15;
  const int lhi = lane >> 4;     // 0..3

  // x staging: thread -> (row = tid>>4, logical 8-float chunk = tid&15),
  // stored at swizzled chunk (c ^ (row&7)) as 8 bf16 = one ds_write_b128.
  const int srow = tid >> 4;
  const int schk = tid & 15;
  const int gx_off = srow * DX + schk * 8;                       // floats
  const int xs_waddr = (srow * 16 + (schk ^ (srow & 7))) * 16;   // bytes

  const int first = blockIdx.x * TPB;

  // prologue: stage tile 0
  {
    const float* xb = x + (size_t)first * TILE_R * DX;
    f32x4 a = *(const f32x4*)(xb + gx_off);
    f32x4 b = *(const f32x4*)(xb + gx_off + 4);
    *(bf16x8*)((char*)xs + xs_waddr) = cvt8(a, b);
  }

  // biases for this wave's expert
  const float bm_lo = bm[wv * MDIM + l15];
  const float bm_hi = bm[wv * MDIM + 16 + l15];
  const float bv_lo = bv[wv * MDIM + l15];
  const float bv_hi = bv[wv * MDIM + 16 + l15];
  const float bg_r = (l15 < KEXP) ? bg[l15] : 0.f;

  // B fragments in registers: ct 0,1 = Wm cols 0..15/16..31; 2,3 = Wv.
  // B layout (16x16x32): k = (lane>>4)*8 + i, col = lane&15.
  bf16x8 bfrag[4][4];
  #pragma unroll
  for (int ct = 0; ct < 4; ++ct) {
    const float* W = (ct < 2 ? Wm : Wv) + (size_t)wv * (DX * MDIM);
    const int mcol = ((ct & 1) << 4) + l15;
    #pragma unroll
    for (int kk = 0; kk < 4; ++kk) {
      bf16x8 tmp;
      #pragma unroll
      for (int i = 0; i < 8; ++i)
        tmp[i] = (__bf16)W[(kk * 32 + lhi * 8 + i) * MDIM + mcol];
      bfrag[ct][kk] = tmp;
    }
  }
  // Gate weight fragments (cols >= KEXP zero-padded)
  bf16x8 wgfrag[2];
  #pragma unroll
  for (int kk = 0; kk < 2; ++kk) {
    bf16x8 tmp;
    #pragma unroll
    for (int i = 0; i < 8; ++i) {
      const int d = kk * 32 + lhi * 8 + i;
      tmp[i] = (__bf16)((l15 < KEXP) ? Wg[d * KEXP + l15] : 0.f);
    }
    wgfrag[kk] = tmp;
  }

  // per-lane direct-read offsets
  const int rtg = wv & 1, jg = wv >> 1;                 // gate slice
  const int t_off = (rtg * 16 + l15) * DT + lhi * 8;    // floats
  const int y_off = lhi * 4 * MDIM + l15;               // floats
  const int swz = l15 & 7;

  float loss_acc = 0.f;
  const float HL2PI = 0.91893853320467274f;   // 0.5*log(2*pi)

  B_LDS();   // tile 0 staged

  for (int it = 0; it < TPB; ++it) {
    const int row0 = (first + it) * TILE_R;
    const int nt = first + ((it + 1 < TPB) ? it + 1 : it);

    // issue next-tile x loads NOW; consumed after the gate barrier (T14)
    const float* nxb = x + (size_t)nt * TILE_R * DX;
    const f32x4 sv0 = *(const f32x4*)(nxb + gx_off);
    const f32x4 sv1 = *(const f32x4*)(nxb + gx_off + 4);

    const float* yb = y + (size_t)row0 * MDIM;
    const float* tb = t + (size_t)row0 * DT;

    // this-iter t fragments (built pre-barrier so gate region has no cold loads)
    const f32x4 tf0 = *(const f32x4*)(tb + t_off);
    const f32x4 tf1 = *(const f32x4*)(tb + t_off + 4);
    const f32x4 tf2 = *(const f32x4*)(tb + t_off + 32);
    const f32x4 tf3 = *(const f32x4*)(tb + t_off + 36);
    const bf16x8 tfrag0 = cvt8(tf0, tf1);
    const bf16x8 tfrag1 = cvt8(tf2, tf3);

    // ---- mean/logvar MFMAs + Gaussian-LL epilogue, per 16-row slab ----
    #pragma unroll
    for (int rt = 0; rt < 2; ++rt) {
      f32x4 acc0 = {0.f,0.f,0.f,0.f}, acc1 = acc0, acc2 = acc0, acc3 = acc0;
      const int abase = l15 * 256 + rt * 4096;          // bytes
      #pragma unroll
      for (int kk = 0; kk < 4; ++kk) {
        const int abyte = abase + (((kk * 4 + lhi) ^ swz) << 4);
        const bf16x8 af = *(const bf16x8*)((const char*)xs + abyte);
        acc0 = MFMA16(af, bfrag[0][kk], acc0);
        acc1 = MFMA16(af, bfrag[1][kk], acc1);
        acc2 = MFMA16(af, bfrag[2][kk], acc2);
        acc3 = MFMA16(af, bfrag[3][kk], acc3);
      }
      // C/D layout: col = lane&15, row = (lane>>4)*4 + j
      #pragma unroll
      for (int j = 0; j < 4; ++j) {
        const int r = rt * 16 + lhi * 4 + j;
        const float y0 = yb[y_off + rt * 512 + j * MDIM];
        const float y1 = yb[y_off + rt * 512 + j * MDIM + 16];
        const float mean0 = acc0[j] + bm_lo;
        const float mean1 = acc1[j] + bm_hi;
        const float lv0 = acc2[j] + bv_lo;
        const float lv1 = acc3[j] + bv_hi;
        const float d0 = y0 - mean0, d1 = y1 - mean1;
        float s = d0 * d0 * (0.5f * __expf(-lv0)) + 0.5f * lv0
                + d1 * d1 * (0.5f * __expf(-lv1)) + 0.5f * lv1;
        s += __shfl_xor(s, 1);
        s += __shfl_xor(s, 2);
        s += __shfl_xor(s, 4);
        s += __shfl_xor(s, 8);
        if (l15 == 0) ll_s[r * 17 + wv] = -(s + MDIM * HL2PI);
      }
    }
    B_LDS();    // ll_s visible; x loads stay in flight

    // ---- gate MFMA + per-row double-LSE; wave owns (rtg,jg) slice ----
    {
      f32x4 g = {0.f,0.f,0.f,0.f};
      g = MFMA16(tfrag0, wgfrag[0], g);
      g = MFMA16(tfrag1, wgfrag[1], g);
      const int rr = rtg * 16 + lhi * 4 + jg;
      const float logit = g[jg] + bg_r;          // lanes l15>=8: zeros, unused
      const float ll = ll_s[rr * 17 + l15];      // lanes l15>=8: garbage, isolated
      const float a = logit + ll;
      float mg = logit, ma = a;
      mg = fmaxf(mg, __shfl_xor(mg, 1));
      mg = fmaxf(mg, __shfl_xor(mg, 2));
      mg = fmaxf(mg, __shfl_xor(mg, 4));
      ma = fmaxf(ma, __shfl_xor(ma, 1));
      ma = fmaxf(ma, __shfl_xor(ma, 2));
      ma = fmaxf(ma, __shfl_xor(ma, 4));
      float eg = __expf(logit - mg);
      float ea = __expf(a - ma);
      eg += __shfl_xor(eg, 1); eg += __shfl_xor(eg, 2); eg += __shfl_xor(eg, 4);
      ea += __shfl_xor(ea, 1); ea += __shfl_xor(ea, 2); ea += __shfl_xor(ea, 4);
      if (l15 == 0) loss_acc += (mg + __logf(eg)) - (ma + __logf(ea));
    }

    // stage next tile (waits its own vmcnt implicitly; issued ~1 phase ago)
    *(bf16x8*)((char*)xs + xs_waddr) = cvt8(sv0, sv1);
    B_LDS();    // xs ready for next iter; ll_s WAR-safe
  }

  // block reduction of loss
  loss_acc += __shfl_xor(loss_acc, 1);
  loss_acc += __shfl_xor(loss_acc, 2);
  loss_acc += __shfl_xor(loss_acc, 4);
  loss_acc += __shfl_xor(loss_acc, 8);
  loss_acc += __shfl_xor(loss_acc, 16);
  loss_acc += __shfl_xor(loss_acc, 32);
  if (lane == 0) red_s[wv] = loss_acc;
  __syncthreads();
  if (tid == 0) {
    float s = 0.f;
    #pragma unroll
    for (int w = 0; w < 8; ++w) s += red_s[w];
    if (partials) partials[blockIdx.x] = s;
    else atomicAdd(out_atomic, s);
  }
}

__global__ void mdn_reg(const float* __restrict__ Wm, const float* __restrict__ Wv,
                        const float* __restrict__ Wg, float* __restrict__ partials,
                        float* __restrict__ out_atomic)
{
  __shared__ float red[4];
  const int gid = blockIdx.x * 256 + threadIdx.x;
  const int stride = 64 * 256;
  float s = 0.f;
  for (int i = gid; i < DX * MDIM * KEXP; i += stride) { float w = Wm[i]; s += w * w; }
  for (int i = gid; i < DX * MDIM * KEXP; i += stride) { float w = Wv[i]; s += w * w; }
  for (int i = gid; i < DT * KEXP; i += stride)        { float w = Wg[i]; s += w * w; }
  s += __shfl_xor(s, 1);
  s += __shfl_xor(s, 2);
  s += __shfl_xor(s, 4);
  s += __shfl_xor(s, 8);
  s += __shfl_xor(s, 16);
  s += __shfl_xor(s, 32);
  if ((threadIdx.x & 63) == 0) red[threadIdx.x >> 6] = s;
  __syncthreads();
  if (threadIdx.x == 0) {
    float b = red[0] + red[1] + red[2] + red[3];
    if (partials) partials[GRID_MAIN + blockIdx.x] = b;
    else atomicAdd(out_atomic, b);
  }
}

__global__ void mdn_final(const float* __restrict__ partials, float* __restrict__ out)
{
  __shared__ float red[4];
  float s = 0.f;
  for (int i = threadIdx.x; i < GRID_MAIN + 64; i += 256) s += partials[i];
  s += __shfl_xor(s, 1);
  s += __shfl_xor(s, 2);
  s += __shfl_xor(s, 4);
  s += __shfl_xor(s, 8);
  s += __shfl_xor(s, 16);
  s += __shfl_xor(s, 32);
  if ((threadIdx.x & 63) == 0) red[threadIdx.x >> 6] = s;
  __syncthreads();
  if (threadIdx.x == 0) out[0] = red[0] + red[1] + red[2] + red[3];
}

extern "C" void kernel_launch(void* const* d_in, const int* in_sizes, int n_in,
                              void* d_out, int out_size, void* d_ws, size_t ws_size,
                              hipStream_t stream)
{
  const float* x  = (const float*)d_in[0];
  const float* t  = (const float*)d_in[1];
  const float* y  = (const float*)d_in[2];
  const float* Wm = (const float*)d_in[3];
  const float* bm = (const float*)d_in[4];
  const float* Wv = (const float*)d_in[5];
  const float* bv = (const float*)d_in[6];
  const float* Wg = (const float*)d_in[7];
  const float* bg = (const float*)d_in[8];
  float* out = (float*)d_out;

  if (ws_size >= (GRID_MAIN + 64) * sizeof(float)) {
    float* partials = (float*)d_ws;
    mdn_main<<<GRID_MAIN, THREADS, 0, stream>>>(x, t, y, Wm, bm, Wv, bv, Wg, bg,
                                                partials, nullptr);
    mdn_reg<<<64, 256, 0, stream>>>(Wm, Wv, Wg, partials, nullptr);
    mdn_final<<<1, 256, 0, stream>>>(partials, out);
  } else {
    hipMemsetAsync(out, 0, sizeof(float), stream);
    mdn_main<<<GRID_MAIN, THREADS, 0, stream>>>(x, t, y, Wm, bm, Wv, bv, Wg, bg,
                                                nullptr, out);
    mdn_reg<<<64, 256, 0, stream>>>(Wm, Wv, Wg, nullptr, out);
  }
}

// Round 5
// 326.679 us; speedup vs baseline: 1.2134x; 1.2134x over previous
//
#include <hip/hip_runtime.h>
#include <hip/hip_bf16.h>

// MDN NLL, fully fused. N=524288 Dx=128 Dt=64 M=32 K=8.
// Memory-bound target: 470 MB reads -> ~75us floor at 6.3 TB/s.
// R5 design: launch_bounds(512,4) => 128-reg cap => 2 blocks/CU. ALL streams
// (x,t,y) reg-staged into LDS one full iteration ahead (T14): loads issue at
// iter top, ds_write at iter bottom => vmcnt waits land ~4000cy after issue.
// 2 lgkm-only barriers/iter, zero vmcnt drains. Register diet: t/y/wg
// fragments live in LDS, not loop-carried regs.
// R2 lesson: 64-VGPR cap + high demand -> 115MB spill. R3/R4 lesson:
// (512,2) lets allocator use 256 regs -> 1 block/CU -> latency-bound.

#define NN 524288
#define DX 128
#define DT 64
#define MDIM 32
#define KEXP 8
#define TILE_R 32
#define THREADS 512
#define GRID_MAIN 512
#define TILES_TOTAL (NN / TILE_R)        // 16384
#define TPB (TILES_TOTAL / GRID_MAIN)    // 32

typedef __bf16 bf16x8 __attribute__((ext_vector_type(8)));
typedef __bf16 bf16x4 __attribute__((ext_vector_type(4)));
typedef float f32x4 __attribute__((ext_vector_type(4)));
typedef float f32x2 __attribute__((ext_vector_type(2)));

__device__ __forceinline__ bf16x8 cvt8(const f32x4 a, const f32x4 b) {
  bf16x8 r;
  r[0] = (__bf16)a[0]; r[1] = (__bf16)a[1]; r[2] = (__bf16)a[2]; r[3] = (__bf16)a[3];
  r[4] = (__bf16)b[0]; r[5] = (__bf16)b[1]; r[6] = (__bf16)b[2]; r[7] = (__bf16)b[3];
  return r;
}
__device__ __forceinline__ bf16x4 cvt4(const f32x4 a) {
  bf16x4 r;
  r[0] = (__bf16)a[0]; r[1] = (__bf16)a[1]; r[2] = (__bf16)a[2]; r[3] = (__bf16)a[3];
  return r;
}

#define MFMA16(a, b, c) __builtin_amdgcn_mfma_f32_16x16x32_bf16(a, b, c, 0, 0, 0)

// LDS-only barrier: global loads stay in flight across it (rule 18 fence).
#define B_LDS() do { \
  asm volatile("s_waitcnt lgkmcnt(0)" ::: "memory"); \
  __builtin_amdgcn_s_barrier(); \
  __builtin_amdgcn_sched_barrier(0); } while (0)

__global__ __launch_bounds__(THREADS, 4) void mdn_main(
    const float* __restrict__ x, const float* __restrict__ t,
    const float* __restrict__ y, const float* __restrict__ Wm,
    const float* __restrict__ bm, const float* __restrict__ Wv,
    const float* __restrict__ bv, const float* __restrict__ Wg,
    const float* __restrict__ bg, float* __restrict__ partials,
    float* __restrict__ out_atomic)
{
  __shared__ __align__(16) unsigned short xs[TILE_R * DX];      // bf16, 8 KB
  __shared__ __align__(16) unsigned short ts[2][TILE_R * DT];   // bf16, 2x4 KB
  __shared__ float ys[TILE_R * 34];                             // f32 pad+2, 4.25 KB
  __shared__ __align__(16) unsigned short wg_lds[2 * 64 * 8];   // 2 KB
  __shared__ float ll_s[TILE_R * 17];                           // 2.2 KB
  __shared__ float red_s[8];

  const int tid = threadIdx.x;
  const int lane = tid & 63;
  const int wv = tid >> 6;       // wave id == expert k
  const int l15 = lane & 15;
  const int lhi = lane >> 4;     // 0..3
  const int swz = l15 & 7;

  // staging geometry: row = tid>>4, 16 threads/row
  const int srow = tid >> 4;
  const int schk = tid & 15;
  const int r7 = srow & 7;
  const int gx_off = srow * DX + schk * 8;                        // 8 floats
  const int xs_waddr = srow * 256 + ((schk ^ r7) << 4);           // bytes
  const int gt_off = srow * DT + schk * 4;                        // 4 floats
  const int ts_waddr = srow * 128 + (((schk >> 1) ^ r7) << 4) + ((schk & 1) << 3);
  const int gy_off = srow * MDIM + schk * 2;                      // 2 floats
  const int ys_widx = srow * 34 + schk * 2;                       // floats

  const int first = blockIdx.x * TPB;

  // ---- prologue: issue tile-0 loads FIRST (hide under weight building) ----
  const float* xb0 = x + (size_t)first * TILE_R * DX;
  const float* tb0 = t + (size_t)first * TILE_R * DT;
  const float* yb0 = y + (size_t)first * TILE_R * MDIM;
  f32x4 sx0 = *(const f32x4*)(xb0 + gx_off);
  f32x4 sx1 = *(const f32x4*)(xb0 + gx_off + 4);
  f32x4 st0 = *(const f32x4*)(tb0 + gt_off);
  f32x2 sy0 = *(const f32x2*)(yb0 + gy_off);

  // biases for this wave's expert
  const float bm_lo = bm[wv * MDIM + l15];
  const float bm_hi = bm[wv * MDIM + 16 + l15];
  const float bv_lo = bv[wv * MDIM + l15];
  const float bv_hi = bv[wv * MDIM + 16 + l15];
  const float bg_r = (l15 < KEXP) ? bg[l15] : 0.f;

  // B fragments: ct 0,1 = Wm cols 0..15/16..31; 2,3 = Wv.
  // B layout (16x16x32): k = (lane>>4)*8 + i, col = lane&15.
  bf16x8 bfrag[4][4];
  #pragma unroll
  for (int ct = 0; ct < 4; ++ct) {
    const float* W = (ct < 2 ? Wm : Wv) + (size_t)wv * (DX * MDIM);
    const int mcol = ((ct & 1) << 4) + l15;
    #pragma unroll
    for (int kk = 0; kk < 4; ++kk) {
      bf16x8 tmp;
      #pragma unroll
      for (int i = 0; i < 8; ++i)
        tmp[i] = (__bf16)W[(kk * 32 + lhi * 8 + i) * MDIM + mcol];
      bfrag[ct][kk] = tmp;
    }
  }
  // Gate weight fragments -> LDS (not loop-carried)
  #pragma unroll
  for (int kk = 0; kk < 2; ++kk) {
    bf16x8 tmp;
    #pragma unroll
    for (int i = 0; i < 8; ++i) {
      const int d = kk * 32 + lhi * 8 + i;
      tmp[i] = (__bf16)((l15 < KEXP) ? Wg[d * KEXP + l15] : 0.f);
    }
    *(bf16x8*)((char*)wg_lds + (kk * 64 + lane) * 16) = tmp;
  }

  // stage tile 0 (implicit vmcnt waits here, overlapped with W reads above)
  *(bf16x8*)((char*)xs + xs_waddr) = cvt8(sx0, sx1);
  *(bf16x4*)((char*)ts[0] + ts_waddr) = cvt4(st0);
  *(f32x2*)(ys + ys_widx) = sy0;
  B_LDS();

  const int rtg = wv & 1, jg = wv >> 1;   // gate slice for this wave
  float loss_acc = 0.f;
  const float HL2PI = 0.91893853320467274f;   // 0.5*log(2*pi)

  for (int it = 0; it < TPB; ++it) {
    const int cur = it & 1;
    const int nt = first + ((it + 1 < TPB) ? it + 1 : it);

    // ---- region A: issue next-tile loads (consumed in region B restage) ----
    const float* xb = x + (size_t)nt * TILE_R * DX;
    const float* tb = t + (size_t)nt * TILE_R * DT;
    const float* yb = y + (size_t)nt * TILE_R * MDIM;
    sx0 = *(const f32x4*)(xb + gx_off);
    sx1 = *(const f32x4*)(xb + gx_off + 4);
    st0 = *(const f32x4*)(tb + gt_off);
    sy0 = *(const f32x2*)(yb + gy_off);

    // ---- mean/logvar MFMAs + Gaussian-LL epilogue, per 16-row slab ----
    #pragma unroll
    for (int rt = 0; rt < 2; ++rt) {
      f32x4 acc0 = {0.f,0.f,0.f,0.f}, acc1 = acc0, acc2 = acc0, acc3 = acc0;
      const int abase = l15 * 256 + rt * 4096;          // bytes
      #pragma unroll
      for (int kk = 0; kk < 4; ++kk) {
        const int abyte = abase + (((kk * 4 + lhi) ^ swz) << 4);
        const bf16x8 af = *(const bf16x8*)((const char*)xs + abyte);
        acc0 = MFMA16(af, bfrag[0][kk], acc0);
        acc1 = MFMA16(af, bfrag[1][kk], acc1);
        acc2 = MFMA16(af, bfrag[2][kk], acc2);
        acc3 = MFMA16(af, bfrag[3][kk], acc3);
      }
      // C/D layout: col = lane&15, row = (lane>>4)*4 + j
      #pragma unroll
      for (int j = 0; j < 4; ++j) {
        const int r = rt * 16 + lhi * 4 + j;
        const float y0 = ys[r * 34 + l15];
        const float y1 = ys[r * 34 + 16 + l15];
        const float mean0 = acc0[j] + bm_lo;
        const float mean1 = acc1[j] + bm_hi;
        const float lv0 = acc2[j] + bv_lo;
        const float lv1 = acc3[j] + bv_hi;
        const float d0 = y0 - mean0, d1 = y1 - mean1;
        float s = d0 * d0 * (0.5f * __expf(-lv0)) + 0.5f * lv0
                + d1 * d1 * (0.5f * __expf(-lv1)) + 0.5f * lv1;
        s += __shfl_xor(s, 1);
        s += __shfl_xor(s, 2);
        s += __shfl_xor(s, 4);
        s += __shfl_xor(s, 8);
        if (l15 == 0) ll_s[r * 17 + wv] = -(s + MDIM * HL2PI);
      }
    }
    B_LDS();    // #1: ll_s visible; xs/ys reads done

    // ---- region B: gate (reads ts[cur], wg_lds, ll_s) + restage ----
    {
      f32x4 g = {0.f,0.f,0.f,0.f};
      #pragma unroll
      for (int kk = 0; kk < 2; ++kk) {
        const int tbyte = (rtg * 16 + l15) * 128 + (((kk * 4 + lhi) ^ swz) << 4);
        const bf16x8 tf = *(const bf16x8*)((const char*)ts[cur] + tbyte);
        const bf16x8 wf = *(const bf16x8*)((const char*)wg_lds + (kk * 64 + lane) * 16);
        g = MFMA16(tf, wf, g);
      }
      const int rr = rtg * 16 + lhi * 4 + jg;
      const float logit = g[jg] + bg_r;          // lanes l15>=8: zeros, unused
      const float ll = ll_s[rr * 17 + l15];      // lanes l15>=8: garbage, isolated
      const float a = logit + ll;
      float mg = logit, ma = a;
      mg = fmaxf(mg, __shfl_xor(mg, 1));
      mg = fmaxf(mg, __shfl_xor(mg, 2));
      mg = fmaxf(mg, __shfl_xor(mg, 4));
      ma = fmaxf(ma, __shfl_xor(ma, 1));
      ma = fmaxf(ma, __shfl_xor(ma, 2));
      ma = fmaxf(ma, __shfl_xor(ma, 4));
      float eg = __expf(logit - mg);
      float ea = __expf(a - ma);
      eg += __shfl_xor(eg, 1); eg += __shfl_xor(eg, 2); eg += __shfl_xor(eg, 4);
      ea += __shfl_xor(ea, 1); ea += __shfl_xor(ea, 2); ea += __shfl_xor(ea, 4);
      if (l15 == 0) loss_acc += (mg + __logf(eg)) - (ma + __logf(ea));
    }

    // restage next tile: xs/ys single-buffered (reads were all in region A),
    // ts double-buffered (gate just read ts[cur] in this region)
    *(bf16x8*)((char*)xs + xs_waddr) = cvt8(sx0, sx1);
    *(bf16x4*)((char*)ts[cur ^ 1] + ts_waddr) = cvt4(st0);
    *(f32x2*)(ys + ys_widx) = sy0;
    B_LDS();    // #2: stages visible for next iter
  }

  // block reduction of loss
  loss_acc += __shfl_xor(loss_acc, 1);
  loss_acc += __shfl_xor(loss_acc, 2);
  loss_acc += __shfl_xor(loss_acc, 4);
  loss_acc += __shfl_xor(loss_acc, 8);
  loss_acc += __shfl_xor(loss_acc, 16);
  loss_acc += __shfl_xor(loss_acc, 32);
  if (lane == 0) red_s[wv] = loss_acc;
  __syncthreads();
  if (tid == 0) {
    float s = 0.f;
    #pragma unroll
    for (int w = 0; w < 8; ++w) s += red_s[w];
    if (partials) partials[blockIdx.x] = s;
    else atomicAdd(out_atomic, s);
  }
}

__global__ void mdn_reg(const float* __restrict__ Wm, const float* __restrict__ Wv,
                        const float* __restrict__ Wg, float* __restrict__ partials,
                        float* __restrict__ out_atomic)
{
  __shared__ float red[4];
  const int gid = blockIdx.x * 256 + threadIdx.x;
  const int stride = 64 * 256;
  float s = 0.f;
  for (int i = gid; i < DX * MDIM * KEXP; i += stride) { float w = Wm[i]; s += w * w; }
  for (int i = gid; i < DX * MDIM * KEXP; i += stride) { float w = Wv[i]; s += w * w; }
  for (int i = gid; i < DT * KEXP; i += stride)        { float w = Wg[i]; s += w * w; }
  s += __shfl_xor(s, 1);
  s += __shfl_xor(s, 2);
  s += __shfl_xor(s, 4);
  s += __shfl_xor(s, 8);
  s += __shfl_xor(s, 16);
  s += __shfl_xor(s, 32);
  if ((threadIdx.x & 63) == 0) red[threadIdx.x >> 6] = s;
  __syncthreads();
  if (threadIdx.x == 0) {
    float b = red[0] + red[1] + red[2] + red[3];
    if (partials) partials[GRID_MAIN + blockIdx.x] = b;
    else atomicAdd(out_atomic, b);
  }
}

__global__ void mdn_final(const float* __restrict__ partials, float* __restrict__ out)
{
  __shared__ float red[4];
  float s = 0.f;
  for (int i = threadIdx.x; i < GRID_MAIN + 64; i += 256) s += partials[i];
  s += __shfl_xor(s, 1);
  s += __shfl_xor(s, 2);
  s += __shfl_xor(s, 4);
  s += __shfl_xor(s, 8);
  s += __shfl_xor(s, 16);
  s += __shfl_xor(s, 32);
  if ((threadIdx.x & 63) == 0) red[threadIdx.x >> 6] = s;
  __syncthreads();
  if (threadIdx.x == 0) out[0] = red[0] + red[1] + red[2] + red[3];
}

extern "C" void kernel_launch(void* const* d_in, const int* in_sizes, int n_in,
                              void* d_out, int out_size, void* d_ws, size_t ws_size,
                              hipStream_t stream)
{
  const float* x  = (const float*)d_in[0];
  const float* t  = (const float*)d_in[1];
  const float* y  = (const float*)d_in[2];
  const float* Wm = (const float*)d_in[3];
  const float* bm = (const float*)d_in[4];
  const float* Wv = (const float*)d_in[5];
  const float* bv = (const float*)d_in[6];
  const float* Wg = (const float*)d_in[7];
  const float* bg = (const float*)d_in[8];
  float* out = (float*)d_out;

  if (ws_size >= (GRID_MAIN + 64) * sizeof(float)) {
    float* partials = (float*)d_ws;
    mdn_main<<<GRID_MAIN, THREADS, 0, stream>>>(x, t, y, Wm, bm, Wv, bv, Wg, bg,
                                                partials, nullptr);
    mdn_reg<<<64, 256, 0, stream>>>(Wm, Wv, Wg, partials, nullptr);
    mdn_final<<<1, 256, 0, stream>>>(partials, out);
  } else {
    hipMemsetAsync(out, 0, sizeof(float), stream);
    mdn_main<<<GRID_MAIN, THREADS, 0, stream>>>(x, t, y, Wm, bm, Wv, bv, Wg, bg,
                                                nullptr, out);
    mdn_reg<<<64, 256, 0, stream>>>(Wm, Wv, Wg, nullptr, out);
  }
}

// Round 6
// 289.868 us; speedup vs baseline: 1.3675x; 1.1270x over previous
//
#include <hip/hip_runtime.h>
#include <hip/hip_bf16.h>

// MDN NLL, fully fused. N=524288 Dx=128 Dt=64 M=32 K=8.
// Memory-bound target: 470 MB reads -> ~75us floor at 6.3 TB/s.
// R6 design: ALL streams (x,t,y) staged f32 via global_load_lds DMA
// (zero staging registers), double-buffered; counted vmcnt waits
// (vmcnt(4)/vmcnt(3), never 0) so next-tile DMA stays in flight across
// barriers; 2 lgkm-only barriers/iter. Gate LDS reads pulled BEFORE
// barrier #2 (all cur-buffer reads done before next DMA issue).
// R2/R5 lesson: spill at 128-cap unless demand <=128 -> no staging regs.
// R3/R4 lesson: 1 blk/CU + exposed latency = 273-396us.

#define NN 524288
#define DX 128
#define DT 64
#define MDIM 32
#define KEXP 8
#define TILE_R 32
#define THREADS 512
#define GRID_MAIN 512
#define TILES_TOTAL (NN / TILE_R)        // 16384
#define TPB (TILES_TOTAL / GRID_MAIN)    // 32

typedef __bf16 bf16x8 __attribute__((ext_vector_type(8)));
typedef float f32x4 __attribute__((ext_vector_type(4)));

__device__ __forceinline__ void glds16(const float* g, float* l) {
  __builtin_amdgcn_global_load_lds(
      (const __attribute__((address_space(1))) unsigned int*)g,
      (__attribute__((address_space(3))) unsigned int*)l, 16, 0, 0);
}

__device__ __forceinline__ bf16x8 cvt8(const f32x4 a, const f32x4 b) {
  bf16x8 r;
  r[0] = (__bf16)a[0]; r[1] = (__bf16)a[1]; r[2] = (__bf16)a[2]; r[3] = (__bf16)a[3];
  r[4] = (__bf16)b[0]; r[5] = (__bf16)b[1]; r[6] = (__bf16)b[2]; r[7] = (__bf16)b[3];
  return r;
}

#define MFMA16(a, b, c) __builtin_amdgcn_mfma_f32_16x16x32_bf16(a, b, c, 0, 0, 0)

__global__ __launch_bounds__(THREADS, 4) void mdn_main(
    const float* __restrict__ x, const float* __restrict__ t,
    const float* __restrict__ y, const float* __restrict__ Wm,
    const float* __restrict__ bm, const float* __restrict__ Wv,
    const float* __restrict__ bv, const float* __restrict__ Wg,
    const float* __restrict__ bg, float* __restrict__ partials,
    float* __restrict__ out_atomic)
{
  __shared__ float xs[2][TILE_R * DX];                          // 2 x 16 KB
  __shared__ float ts2[2][TILE_R * DT];                         // 2 x 8 KB
  __shared__ float ys2[2][TILE_R * MDIM];                       // 2 x 4 KB
  __shared__ __align__(16) unsigned short wg_lds[2 * 64 * 8];   // 2 KB
  __shared__ float ll_s[TILE_R * 17];                           // 2.2 KB
  __shared__ float red_s[8];

  const int tid = threadIdx.x;
  const int lane = tid & 63;
  const int wv = tid >> 6;       // wave id == expert k
  const int l15 = lane & 15;
  const int lhi = lane >> 4;     // 0..3
  const int swz = l15 & 7;

  // DMA chunk assignment (16B chunks). Source pre-swizzled: LDS slot s of
  // row r holds global chunk (s&~7)|((s&7)^(r&7)) -- involution.
  const int ch0 = (wv * 2 + 0) * 64 + lane;            // x: 1024 chunks
  const int ch1 = (wv * 2 + 1) * 64 + lane;
  const int xr0 = ch0 >> 5, xr1 = ch1 >> 5;
  const int x0off = xr0 * DX + (((ch0 & 31) ^ (xr0 & 7)) << 2);
  const int x1off = xr1 * DX + (((ch1 & 31) ^ (xr1 & 7)) << 2);
  const int cht = wv * 64 + lane;                      // t: 512 chunks
  const int tr = cht >> 4;
  const int t0off = tr * DT + (((cht & 15) ^ (tr & 7)) << 2);
  const int chy = wv * 64 + lane;                      // y: 256 chunks (wv<4)
  const int yr = chy >> 3;
  const int y0off = yr * MDIM + (((chy & 7) ^ (yr & 7)) << 2);

  const int first = blockIdx.x * TPB;

  auto issue_batch = [&](int tile, int buf) {
    const size_t base = (size_t)tile * TILE_R;
    const float* xb = x + base * DX;
    const float* tb = t + base * DT;
    glds16(xb + x0off, &xs[buf][ch0 * 4]);
    glds16(xb + x1off, &xs[buf][ch1 * 4]);
    glds16(tb + t0off, &ts2[buf][cht * 4]);
    if (wv < 4) glds16(y + base * MDIM + y0off, &ys2[buf][chy * 4]);
  };

  issue_batch(first, 0);   // overlap tile-0 DMA with weight prologue

  // biases for this wave's expert
  const float bm_lo = bm[wv * MDIM + l15];
  const float bm_hi = bm[wv * MDIM + 16 + l15];
  const float bv_lo = bv[wv * MDIM + l15];
  const float bv_hi = bv[wv * MDIM + 16 + l15];
  const float bg_r = (l15 < KEXP) ? bg[l15] : 0.f;

  // B fragments: ct 0,1 = Wm cols 0..15/16..31; 2,3 = Wv.
  // B layout (16x16x32): k = (lane>>4)*8 + i, col = lane&15.
  bf16x8 bfrag[4][4];
  #pragma unroll
  for (int ct = 0; ct < 4; ++ct) {
    const float* W = (ct < 2 ? Wm : Wv) + (size_t)wv * (DX * MDIM);
    const int mcol = ((ct & 1) << 4) + l15;
    #pragma unroll
    for (int kk = 0; kk < 4; ++kk) {
      bf16x8 tmp;
      #pragma unroll
      for (int i = 0; i < 8; ++i)
        tmp[i] = (__bf16)W[(kk * 32 + lhi * 8 + i) * MDIM + mcol];
      bfrag[ct][kk] = tmp;
    }
  }
  // Gate weight fragments -> LDS (cols >= KEXP zero-padded)
  #pragma unroll
  for (int kk = 0; kk < 2; ++kk) {
    bf16x8 tmp;
    #pragma unroll
    for (int i = 0; i < 8; ++i) {
      const int d = kk * 32 + lhi * 8 + i;
      tmp[i] = (__bf16)((l15 < KEXP) ? Wg[d * KEXP + l15] : 0.f);
    }
    *(bf16x8*)((char*)wg_lds + (kk * 64 + lane) * 16) = tmp;
  }

  // prologue drain (once): tile-0 DMA + wg_lds writes visible
  asm volatile("s_waitcnt vmcnt(0) lgkmcnt(0)" ::: "memory");
  __builtin_amdgcn_s_barrier();
  __builtin_amdgcn_sched_barrier(0);

  const int rtg = wv & 1, jg = wv >> 1;   // gate slice for this wave
  float loss_acc = 0.f;
  const float HL2PI = 0.91893853320467274f;   // 0.5*log(2*pi)

  for (int it = 0; it < TPB; ++it) {
    const int cur = it & 1;

    // issue next-tile DMA (stays in flight across both barriers)
    issue_batch(first + ((it + 1 < TPB) ? it + 1 : it), cur ^ 1);
    // counted wait: all but my new batch retired => tile `it` landed
    if (wv < 4) asm volatile("s_waitcnt vmcnt(4)" ::: "memory");
    else        asm volatile("s_waitcnt vmcnt(3)" ::: "memory");
    __builtin_amdgcn_s_barrier();
    __builtin_amdgcn_sched_barrier(0);

    const float* xc = xs[cur];
    const float* yc = ys2[cur];

    // ---- mean/logvar MFMAs + Gaussian-LL epilogue, per 16-row slab ----
    #pragma unroll
    for (int rt = 0; rt < 2; ++rt) {
      f32x4 acc0 = {0.f,0.f,0.f,0.f}, acc1 = acc0, acc2 = acc0, acc3 = acc0;
      const int rbase = (rt * 16 + l15) * DX;
      #pragma unroll
      for (int kk = 0; kk < 4; ++kk) {
        const f32x4 f0 = *(const f32x4*)&xc[rbase + kk * 32 + (((lhi * 2 + 0) ^ swz) << 2)];
        const f32x4 f1 = *(const f32x4*)&xc[rbase + kk * 32 + (((lhi * 2 + 1) ^ swz) << 2)];
        const bf16x8 af = cvt8(f0, f1);
        acc0 = MFMA16(af, bfrag[0][kk], acc0);
        acc1 = MFMA16(af, bfrag[1][kk], acc1);
        acc2 = MFMA16(af, bfrag[2][kk], acc2);
        acc3 = MFMA16(af, bfrag[3][kk], acc3);
      }
      // C/D layout: col = lane&15, row = (lane>>4)*4 + j
      #pragma unroll
      for (int j = 0; j < 4; ++j) {
        const int r = rt * 16 + lhi * 4 + j;
        const int r7 = r & 7;
        const float y0 = yc[r * MDIM + ((((l15 >> 2)    ) ^ r7) << 2) + (l15 & 3)];
        const float y1 = yc[r * MDIM + ((((l15 >> 2) + 4) ^ r7) << 2) + (l15 & 3)];
        const float mean0 = acc0[j] + bm_lo;
        const float mean1 = acc1[j] + bm_hi;
        const float lv0 = acc2[j] + bv_lo;
        const float lv1 = acc3[j] + bv_hi;
        const float d0 = y0 - mean0, d1 = y1 - mean1;
        float s = d0 * d0 * (0.5f * __expf(-lv0)) + 0.5f * lv0
                + d1 * d1 * (0.5f * __expf(-lv1)) + 0.5f * lv1;
        s += __shfl_xor(s, 1);
        s += __shfl_xor(s, 2);
        s += __shfl_xor(s, 4);
        s += __shfl_xor(s, 8);
        if (l15 == 0) ll_s[r * 17 + wv] = -(s + MDIM * HL2PI);
      }
    }

    // ---- gate MFMA (reads ts2[cur] + wg_lds) BEFORE barrier #2, so all
    // cur-buffer reads complete before the next DMA issue ----
    float logit;
    {
      const float* tc = ts2[cur];
      const int rb = (rtg * 16 + l15) * DT;
      f32x4 g = {0.f,0.f,0.f,0.f};
      #pragma unroll
      for (int kk = 0; kk < 2; ++kk) {
        const f32x4 f0 = *(const f32x4*)&tc[rb + kk * 32 + (((lhi * 2 + 0) ^ swz) << 2)];
        const f32x4 f1 = *(const f32x4*)&tc[rb + kk * 32 + (((lhi * 2 + 1) ^ swz) << 2)];
        const bf16x8 wf = *(const bf16x8*)((const char*)wg_lds + (kk * 64 + lane) * 16);
        g = MFMA16(cvt8(f0, f1), wf, g);
      }
      logit = g[jg] + bg_r;                     // lanes l15>=8: zeros, unused
    }

    asm volatile("s_waitcnt lgkmcnt(0)" ::: "memory");
    __builtin_amdgcn_s_barrier();               // #2: ll_s visible
    __builtin_amdgcn_sched_barrier(0);

    // ---- per-row double-LSE over experts (lanes l15 0..7) ----
    {
      const int rr = rtg * 16 + lhi * 4 + jg;
      const float ll = ll_s[rr * 17 + l15];     // lanes l15>=8: garbage, isolated
      const float a = logit + ll;
      float mg = logit, ma = a;
      mg = fmaxf(mg, __shfl_xor(mg, 1));
      mg = fmaxf(mg, __shfl_xor(mg, 2));
      mg = fmaxf(mg, __shfl_xor(mg, 4));
      ma = fmaxf(ma, __shfl_xor(ma, 1));
      ma = fmaxf(ma, __shfl_xor(ma, 2));
      ma = fmaxf(ma, __shfl_xor(ma, 4));
      float eg = __expf(logit - mg);
      float ea = __expf(a - ma);
      eg += __shfl_xor(eg, 1); eg += __shfl_xor(eg, 2); eg += __shfl_xor(eg, 4);
      ea += __shfl_xor(ea, 1); ea += __shfl_xor(ea, 2); ea += __shfl_xor(ea, 4);
      if (l15 == 0) loss_acc += (mg + __logf(eg)) - (ma + __logf(ea));
    }
  }

  // block reduction of loss
  loss_acc += __shfl_xor(loss_acc, 1);
  loss_acc += __shfl_xor(loss_acc, 2);
  loss_acc += __shfl_xor(loss_acc, 4);
  loss_acc += __shfl_xor(loss_acc, 8);
  loss_acc += __shfl_xor(loss_acc, 16);
  loss_acc += __shfl_xor(loss_acc, 32);
  if (lane == 0) red_s[wv] = loss_acc;
  __syncthreads();
  if (tid == 0) {
    float s = 0.f;
    #pragma unroll
    for (int w = 0; w < 8; ++w) s += red_s[w];
    if (partials) partials[blockIdx.x] = s;
    else atomicAdd(out_atomic, s);
  }
}

__global__ void mdn_reg(const float* __restrict__ Wm, const float* __restrict__ Wv,
                        const float* __restrict__ Wg, float* __restrict__ partials,
                        float* __restrict__ out_atomic)
{
  __shared__ float red[4];
  const int gid = blockIdx.x * 256 + threadIdx.x;
  const int stride = 64 * 256;
  float s = 0.f;
  for (int i = gid; i < DX * MDIM * KEXP; i += stride) { float w = Wm[i]; s += w * w; }
  for (int i = gid; i < DX * MDIM * KEXP; i += stride) { float w = Wv[i]; s += w * w; }
  for (int i = gid; i < DT * KEXP; i += stride)        { float w = Wg[i]; s += w * w; }
  s += __shfl_xor(s, 1);
  s += __shfl_xor(s, 2);
  s += __shfl_xor(s, 4);
  s += __shfl_xor(s, 8);
  s += __shfl_xor(s, 16);
  s += __shfl_xor(s, 32);
  if ((threadIdx.x & 63) == 0) red[threadIdx.x >> 6] = s;
  __syncthreads();
  if (threadIdx.x == 0) {
    float b = red[0] + red[1] + red[2] + red[3];
    if (partials) partials[GRID_MAIN + blockIdx.x] = b;
    else atomicAdd(out_atomic, b);
  }
}

__global__ void mdn_final(const float* __restrict__ partials, float* __restrict__ out)
{
  __shared__ float red[4];
  float s = 0.f;
  for (int i = threadIdx.x; i < GRID_MAIN + 64; i += 256) s += partials[i];
  s += __shfl_xor(s, 1);
  s += __shfl_xor(s, 2);
  s += __shfl_xor(s, 4);
  s += __shfl_xor(s, 8);
  s += __shfl_xor(s, 16);
  s += __shfl_xor(s, 32);
  if ((threadIdx.x & 63) == 0) red[threadIdx.x >> 6] = s;
  __syncthreads();
  if (threadIdx.x == 0) out[0] = red[0] + red[1] + red[2] + red[3];
}

extern "C" void kernel_launch(void* const* d_in, const int* in_sizes, int n_in,
                              void* d_out, int out_size, void* d_ws, size_t ws_size,
                              hipStream_t stream)
{
  const float* x  = (const float*)d_in[0];
  const float* t  = (const float*)d_in[1];
  const float* y  = (const float*)d_in[2];
  const float* Wm = (const float*)d_in[3];
  const float* bm = (const float*)d_in[4];
  const float* Wv = (const float*)d_in[5];
  const float* bv = (const float*)d_in[6];
  const float* Wg = (const float*)d_in[7];
  const float* bg = (const float*)d_in[8];
  float* out = (float*)d_out;

  if (ws_size >= (GRID_MAIN + 64) * sizeof(float)) {
    float* partials = (float*)d_ws;
    mdn_main<<<GRID_MAIN, THREADS, 0, stream>>>(x, t, y, Wm, bm, Wv, bv, Wg, bg,
                                                partials, nullptr);
    mdn_reg<<<64, 256, 0, stream>>>(Wm, Wv, Wg, partials, nullptr);
    mdn_final<<<1, 256, 0, stream>>>(partials, out);
  } else {
    hipMemsetAsync(out, 0, sizeof(float), stream);
    mdn_main<<<GRID_MAIN, THREADS, 0, stream>>>(x, t, y, Wm, bm, Wv, bv, Wg, bg,
                                                nullptr, out);
    mdn_reg<<<64, 256, 0, stream>>>(Wm, Wv, Wg, nullptr, out);
  }
}

// Round 7
// 265.720 us; speedup vs baseline: 1.4917x; 1.0909x over previous
//
#include <hip/hip_runtime.h>
#include <hip/hip_bf16.h>

// MDN NLL, fully fused. N=524288 Dx=128 Dt=64 M=32 K=8.
// Memory-bound target: 470 MB reads -> ~75us floor at 6.3 TB/s.
// R7 = R6 structure with (512,2): ALL streams (x,t,y) staged f32 via
// global_load_lds DMA (zero staging registers), double-buffered; counted
// vmcnt waits (vmcnt(4)/vmcnt(3), never 0) so next-tile DMA stays in
// flight across barriers; 2 lgkm-only barriers/iter.
// Register ledger: bfrag=64 + acc/transients/addr ~60 => needs the 256-reg
// budget. (512,4)'s 128-cap spilled 3 dwords/iter into the MFMA chain in
// R2/R5/R6 (WRITE_SIZE 103-176 MB). 1 blk/CU is fine: prefetch is a full
// iter (~5us >> 900cy HBM latency) ahead with counted waits.

#define NN 524288
#define DX 128
#define DT 64
#define MDIM 32
#define KEXP 8
#define TILE_R 32
#define THREADS 512
#define GRID_MAIN 512
#define TILES_TOTAL (NN / TILE_R)        // 16384
#define TPB (TILES_TOTAL / GRID_MAIN)    // 32

typedef __bf16 bf16x8 __attribute__((ext_vector_type(8)));
typedef float f32x4 __attribute__((ext_vector_type(4)));

__device__ __forceinline__ void glds16(const float* g, float* l) {
  __builtin_amdgcn_global_load_lds(
      (const __attribute__((address_space(1))) unsigned int*)g,
      (__attribute__((address_space(3))) unsigned int*)l, 16, 0, 0);
}

__device__ __forceinline__ bf16x8 cvt8(const f32x4 a, const f32x4 b) {
  bf16x8 r;
  r[0] = (__bf16)a[0]; r[1] = (__bf16)a[1]; r[2] = (__bf16)a[2]; r[3] = (__bf16)a[3];
  r[4] = (__bf16)b[0]; r[5] = (__bf16)b[1]; r[6] = (__bf16)b[2]; r[7] = (__bf16)b[3];
  return r;
}

#define MFMA16(a, b, c) __builtin_amdgcn_mfma_f32_16x16x32_bf16(a, b, c, 0, 0, 0)

__global__ __launch_bounds__(THREADS, 2) void mdn_main(
    const float* __restrict__ x, const float* __restrict__ t,
    const float* __restrict__ y, const float* __restrict__ Wm,
    const float* __restrict__ bm, const float* __restrict__ Wv,
    const float* __restrict__ bv, const float* __restrict__ Wg,
    const float* __restrict__ bg, float* __restrict__ partials,
    float* __restrict__ out_atomic)
{
  __shared__ float xs[2][TILE_R * DX];                          // 2 x 16 KB
  __shared__ float ts2[2][TILE_R * DT];                         // 2 x 8 KB
  __shared__ float ys2[2][TILE_R * MDIM];                       // 2 x 4 KB
  __shared__ __align__(16) unsigned short wg_lds[2 * 64 * 8];   // 2 KB
  __shared__ float ll_s[TILE_R * 17];                           // 2.2 KB
  __shared__ float red_s[8];

  const int tid = threadIdx.x;
  const int lane = tid & 63;
  const int wv = tid >> 6;       // wave id == expert k
  const int l15 = lane & 15;
  const int lhi = lane >> 4;     // 0..3
  const int swz = l15 & 7;

  // DMA chunk assignment (16B chunks). Source pre-swizzled: LDS slot s of
  // row r holds global chunk (s&~7)|((s&7)^(r&7)) -- involution.
  const int ch0 = (wv * 2 + 0) * 64 + lane;            // x: 1024 chunks
  const int ch1 = (wv * 2 + 1) * 64 + lane;
  const int xr0 = ch0 >> 5, xr1 = ch1 >> 5;
  const int x0off = xr0 * DX + (((ch0 & 31) ^ (xr0 & 7)) << 2);
  const int x1off = xr1 * DX + (((ch1 & 31) ^ (xr1 & 7)) << 2);
  const int cht = wv * 64 + lane;                      // t: 512 chunks
  const int tr = cht >> 4;
  const int t0off = tr * DT + (((cht & 15) ^ (tr & 7)) << 2);
  const int chy = wv * 64 + lane;                      // y: 256 chunks (wv<4)
  const int yr = chy >> 3;
  const int y0off = yr * MDIM + (((chy & 7) ^ (yr & 7)) << 2);

  const int first = blockIdx.x * TPB;

  auto issue_batch = [&](int tile, int buf) {
    const size_t base = (size_t)tile * TILE_R;
    const float* xb = x + base * DX;
    const float* tb = t + base * DT;
    glds16(xb + x0off, &xs[buf][ch0 * 4]);
    glds16(xb + x1off, &xs[buf][ch1 * 4]);
    glds16(tb + t0off, &ts2[buf][cht * 4]);
    if (wv < 4) glds16(y + base * MDIM + y0off, &ys2[buf][chy * 4]);
  };

  issue_batch(first, 0);   // overlap tile-0 DMA with weight prologue

  // biases for this wave's expert
  const float bm_lo = bm[wv * MDIM + l15];
  const float bm_hi = bm[wv * MDIM + 16 + l15];
  const float bv_lo = bv[wv * MDIM + l15];
  const float bv_hi = bv[wv * MDIM + 16 + l15];
  const float bg_r = (l15 < KEXP) ? bg[l15] : 0.f;

  // B fragments: ct 0,1 = Wm cols 0..15/16..31; 2,3 = Wv.
  // B layout (16x16x32): k = (lane>>4)*8 + i, col = lane&15.
  bf16x8 bfrag[4][4];
  #pragma unroll
  for (int ct = 0; ct < 4; ++ct) {
    const float* W = (ct < 2 ? Wm : Wv) + (size_t)wv * (DX * MDIM);
    const int mcol = ((ct & 1) << 4) + l15;
    #pragma unroll
    for (int kk = 0; kk < 4; ++kk) {
      bf16x8 tmp;
      #pragma unroll
      for (int i = 0; i < 8; ++i)
        tmp[i] = (__bf16)W[(kk * 32 + lhi * 8 + i) * MDIM + mcol];
      bfrag[ct][kk] = tmp;
    }
  }
  // Gate weight fragments -> LDS (cols >= KEXP zero-padded)
  #pragma unroll
  for (int kk = 0; kk < 2; ++kk) {
    bf16x8 tmp;
    #pragma unroll
    for (int i = 0; i < 8; ++i) {
      const int d = kk * 32 + lhi * 8 + i;
      tmp[i] = (__bf16)((l15 < KEXP) ? Wg[d * KEXP + l15] : 0.f);
    }
    *(bf16x8*)((char*)wg_lds + (kk * 64 + lane) * 16) = tmp;
  }

  // prologue drain (once): tile-0 DMA + wg_lds writes visible
  asm volatile("s_waitcnt vmcnt(0) lgkmcnt(0)" ::: "memory");
  __builtin_amdgcn_s_barrier();
  __builtin_amdgcn_sched_barrier(0);

  const int rtg = wv & 1, jg = wv >> 1;   // gate slice for this wave
  float loss_acc = 0.f;
  const float HL2PI = 0.91893853320467274f;   // 0.5*log(2*pi)

  for (int it = 0; it < TPB; ++it) {
    const int cur = it & 1;

    // issue next-tile DMA (stays in flight across both barriers)
    issue_batch(first + ((it + 1 < TPB) ? it + 1 : it), cur ^ 1);
    // counted wait: all but my new batch retired => tile `it` landed
    if (wv < 4) asm volatile("s_waitcnt vmcnt(4)" ::: "memory");
    else        asm volatile("s_waitcnt vmcnt(3)" ::: "memory");
    __builtin_amdgcn_s_barrier();
    __builtin_amdgcn_sched_barrier(0);

    const float* xc = xs[cur];
    const float* yc = ys2[cur];

    // ---- mean/logvar MFMAs + Gaussian-LL epilogue, per 16-row slab ----
    #pragma unroll
    for (int rt = 0; rt < 2; ++rt) {
      f32x4 acc0 = {0.f,0.f,0.f,0.f}, acc1 = acc0, acc2 = acc0, acc3 = acc0;
      const int rbase = (rt * 16 + l15) * DX;
      #pragma unroll
      for (int kk = 0; kk < 4; ++kk) {
        const f32x4 f0 = *(const f32x4*)&xc[rbase + kk * 32 + (((lhi * 2 + 0) ^ swz) << 2)];
        const f32x4 f1 = *(const f32x4*)&xc[rbase + kk * 32 + (((lhi * 2 + 1) ^ swz) << 2)];
        const bf16x8 af = cvt8(f0, f1);
        acc0 = MFMA16(af, bfrag[0][kk], acc0);
        acc1 = MFMA16(af, bfrag[1][kk], acc1);
        acc2 = MFMA16(af, bfrag[2][kk], acc2);
        acc3 = MFMA16(af, bfrag[3][kk], acc3);
      }
      // C/D layout: col = lane&15, row = (lane>>4)*4 + j
      #pragma unroll
      for (int j = 0; j < 4; ++j) {
        const int r = rt * 16 + lhi * 4 + j;
        const int r7 = r & 7;
        const float y0 = yc[r * MDIM + ((((l15 >> 2)    ) ^ r7) << 2) + (l15 & 3)];
        const float y1 = yc[r * MDIM + ((((l15 >> 2) + 4) ^ r7) << 2) + (l15 & 3)];
        const float mean0 = acc0[j] + bm_lo;
        const float mean1 = acc1[j] + bm_hi;
        const float lv0 = acc2[j] + bv_lo;
        const float lv1 = acc3[j] + bv_hi;
        const float d0 = y0 - mean0, d1 = y1 - mean1;
        float s = d0 * d0 * (0.5f * __expf(-lv0)) + 0.5f * lv0
                + d1 * d1 * (0.5f * __expf(-lv1)) + 0.5f * lv1;
        s += __shfl_xor(s, 1);
        s += __shfl_xor(s, 2);
        s += __shfl_xor(s, 4);
        s += __shfl_xor(s, 8);
        if (l15 == 0) ll_s[r * 17 + wv] = -(s + MDIM * HL2PI);
      }
    }

    // ---- gate MFMA (reads ts2[cur] + wg_lds) BEFORE barrier #2, so all
    // cur-buffer reads complete before the next DMA issue ----
    float logit;
    {
      const float* tc = ts2[cur];
      const int rb = (rtg * 16 + l15) * DT;
      f32x4 g = {0.f,0.f,0.f,0.f};
      #pragma unroll
      for (int kk = 0; kk < 2; ++kk) {
        const f32x4 f0 = *(const f32x4*)&tc[rb + kk * 32 + (((lhi * 2 + 0) ^ swz) << 2)];
        const f32x4 f1 = *(const f32x4*)&tc[rb + kk * 32 + (((lhi * 2 + 1) ^ swz) << 2)];
        const bf16x8 wf = *(const bf16x8*)((const char*)wg_lds + (kk * 64 + lane) * 16);
        g = MFMA16(cvt8(f0, f1), wf, g);
      }
      logit = g[jg] + bg_r;                     // lanes l15>=8: zeros, unused
    }

    asm volatile("s_waitcnt lgkmcnt(0)" ::: "memory");
    __builtin_amdgcn_s_barrier();               // #2: ll_s visible
    __builtin_amdgcn_sched_barrier(0);

    // ---- per-row double-LSE over experts (lanes l15 0..7) ----
    {
      const int rr = rtg * 16 + lhi * 4 + jg;
      const float ll = ll_s[rr * 17 + l15];     // lanes l15>=8: garbage, isolated
      const float a = logit + ll;
      float mg = logit, ma = a;
      mg = fmaxf(mg, __shfl_xor(mg, 1));
      mg = fmaxf(mg, __shfl_xor(mg, 2));
      mg = fmaxf(mg, __shfl_xor(mg, 4));
      ma = fmaxf(ma, __shfl_xor(ma, 1));
      ma = fmaxf(ma, __shfl_xor(ma, 2));
      ma = fmaxf(ma, __shfl_xor(ma, 4));
      float eg = __expf(logit - mg);
      float ea = __expf(a - ma);
      eg += __shfl_xor(eg, 1); eg += __shfl_xor(eg, 2); eg += __shfl_xor(eg, 4);
      ea += __shfl_xor(ea, 1); ea += __shfl_xor(ea, 2); ea += __shfl_xor(ea, 4);
      if (l15 == 0) loss_acc += (mg + __logf(eg)) - (ma + __logf(ea));
    }
  }

  // block reduction of loss
  loss_acc += __shfl_xor(loss_acc, 1);
  loss_acc += __shfl_xor(loss_acc, 2);
  loss_acc += __shfl_xor(loss_acc, 4);
  loss_acc += __shfl_xor(loss_acc, 8);
  loss_acc += __shfl_xor(loss_acc, 16);
  loss_acc += __shfl_xor(loss_acc, 32);
  if (lane == 0) red_s[wv] = loss_acc;
  __syncthreads();
  if (tid == 0) {
    float s = 0.f;
    #pragma unroll
    for (int w = 0; w < 8; ++w) s += red_s[w];
    if (partials) partials[blockIdx.x] = s;
    else atomicAdd(out_atomic, s);
  }
}

__global__ void mdn_reg(const float* __restrict__ Wm, const float* __restrict__ Wv,
                        const float* __restrict__ Wg, float* __restrict__ partials,
                        float* __restrict__ out_atomic)
{
  __shared__ float red[4];
  const int gid = blockIdx.x * 256 + threadIdx.x;
  const int stride = 64 * 256;
  float s = 0.f;
  for (int i = gid; i < DX * MDIM * KEXP; i += stride) { float w = Wm[i]; s += w * w; }
  for (int i = gid; i < DX * MDIM * KEXP; i += stride) { float w = Wv[i]; s += w * w; }
  for (int i = gid; i < DT * KEXP; i += stride)        { float w = Wg[i]; s += w * w; }
  s += __shfl_xor(s, 1);
  s += __shfl_xor(s, 2);
  s += __shfl_xor(s, 4);
  s += __shfl_xor(s, 8);
  s += __shfl_xor(s, 16);
  s += __shfl_xor(s, 32);
  if ((threadIdx.x & 63) == 0) red[threadIdx.x >> 6] = s;
  __syncthreads();
  if (threadIdx.x == 0) {
    float b = red[0] + red[1] + red[2] + red[3];
    if (partials) partials[GRID_MAIN + blockIdx.x] = b;
    else atomicAdd(out_atomic, b);
  }
}

__global__ void mdn_final(const float* __restrict__ partials, float* __restrict__ out)
{
  __shared__ float red[4];
  float s = 0.f;
  for (int i = threadIdx.x; i < GRID_MAIN + 64; i += 256) s += partials[i];
  s += __shfl_xor(s, 1);
  s += __shfl_xor(s, 2);
  s += __shfl_xor(s, 4);
  s += __shfl_xor(s, 8);
  s += __shfl_xor(s, 16);
  s += __shfl_xor(s, 32);
  if ((threadIdx.x & 63) == 0) red[threadIdx.x >> 6] = s;
  __syncthreads();
  if (threadIdx.x == 0) out[0] = red[0] + red[1] + red[2] + red[3];
}

extern "C" void kernel_launch(void* const* d_in, const int* in_sizes, int n_in,
                              void* d_out, int out_size, void* d_ws, size_t ws_size,
                              hipStream_t stream)
{
  const float* x  = (const float*)d_in[0];
  const float* t  = (const float*)d_in[1];
  const float* y  = (const float*)d_in[2];
  const float* Wm = (const float*)d_in[3];
  const float* bm = (const float*)d_in[4];
  const float* Wv = (const float*)d_in[5];
  const float* bv = (const float*)d_in[6];
  const float* Wg = (const float*)d_in[7];
  const float* bg = (const float*)d_in[8];
  float* out = (float*)d_out;

  if (ws_size >= (GRID_MAIN + 64) * sizeof(float)) {
    float* partials = (float*)d_ws;
    mdn_main<<<GRID_MAIN, THREADS, 0, stream>>>(x, t, y, Wm, bm, Wv, bv, Wg, bg,
                                                partials, nullptr);
    mdn_reg<<<64, 256, 0, stream>>>(Wm, Wv, Wg, partials, nullptr);
    mdn_final<<<1, 256, 0, stream>>>(partials, out);
  } else {
    hipMemsetAsync(out, 0, sizeof(float), stream);
    mdn_main<<<GRID_MAIN, THREADS, 0, stream>>>(x, t, y, Wm, bm, Wv, bv, Wg, bg,
                                                nullptr, out);
    mdn_reg<<<64, 256, 0, stream>>>(Wm, Wv, Wg, nullptr, out);
  }
}

// Round 8
// 198.675 us; speedup vs baseline: 1.9952x; 1.3375x over previous
//
#include <hip/hip_runtime.h>
#include <hip/hip_bf16.h>

// MDN NLL, fully fused. N=524288 Dx=128 Dt=64 M=32 K=8.
// Memory-bound target: 470 MB reads -> ~75us floor at 6.3 TB/s.
// R8 = R7 pipeline (DMA all streams, counted vmcnt, 2 lgkm barriers/iter)
// + TRANSPOSED MFMA: mfma(W,x) instead of mfma(x,W). A-layout and B-layout
// have identical lane maps (row/col=lane&15, k=lhi*8+i), so the same
// validated fragments compute D[m][r] (sample=col=l15, m=row=lhi*4+j).
// M-reduce becomes in-lane + 2 shfls (was 4-shfl chains x8); y reads become
// 2x ds_read_b128 (was 16 conflicting b32); bias folds into acc init;
// gate LSE becomes in-lane over k + 1 shfl each (was 3-shfl chains x4).
// R2/R5/R6 lesson: 128-reg cap spills 64-reg bfrag -> (512,2).

#define NN 524288
#define DX 128
#define DT 64
#define MDIM 32
#define KEXP 8
#define TILE_R 32
#define THREADS 512
#define GRID_MAIN 512
#define TILES_TOTAL (NN / TILE_R)        // 16384
#define TPB (TILES_TOTAL / GRID_MAIN)    // 32

typedef __bf16 bf16x8 __attribute__((ext_vector_type(8)));
typedef float f32x4 __attribute__((ext_vector_type(4)));

__device__ __forceinline__ void glds16(const float* g, float* l) {
  __builtin_amdgcn_global_load_lds(
      (const __attribute__((address_space(1))) unsigned int*)g,
      (__attribute__((address_space(3))) unsigned int*)l, 16, 0, 0);
}

__device__ __forceinline__ bf16x8 cvt8(const f32x4 a, const f32x4 b) {
  bf16x8 r;
  r[0] = (__bf16)a[0]; r[1] = (__bf16)a[1]; r[2] = (__bf16)a[2]; r[3] = (__bf16)a[3];
  r[4] = (__bf16)b[0]; r[5] = (__bf16)b[1]; r[6] = (__bf16)b[2]; r[7] = (__bf16)b[3];
  return r;
}

#define MFMA16(a, b, c) __builtin_amdgcn_mfma_f32_16x16x32_bf16(a, b, c, 0, 0, 0)

__global__ __launch_bounds__(THREADS, 2) void mdn_main(
    const float* __restrict__ x, const float* __restrict__ t,
    const float* __restrict__ y, const float* __restrict__ Wm,
    const float* __restrict__ bm, const float* __restrict__ Wv,
    const float* __restrict__ bv, const float* __restrict__ Wg,
    const float* __restrict__ bg, float* __restrict__ partials,
    float* __restrict__ out_atomic)
{
  __shared__ float xs[2][TILE_R * DX];                          // 2 x 16 KB
  __shared__ float ts2[2][TILE_R * DT];                         // 2 x 8 KB
  __shared__ float ys2[2][TILE_R * MDIM];                       // 2 x 4 KB
  __shared__ __align__(16) unsigned short wg_lds[2 * 64 * 8];   // 2 KB
  __shared__ float ll_s[TILE_R * 20];                           // 2.5 KB, b128-aligned rows
  __shared__ float red_s[8];

  const int tid = threadIdx.x;
  const int lane = tid & 63;
  const int wv = tid >> 6;       // wave id == expert k
  const int l15 = lane & 15;
  const int lhi = lane >> 4;     // 0..3
  const int swz = l15 & 7;

  // DMA chunk assignment (16B chunks). Source pre-swizzled: LDS slot s of
  // row r holds global chunk (s&~7)|((s&7)^(r&7)) -- involution.
  const int ch0 = (wv * 2 + 0) * 64 + lane;            // x: 1024 chunks
  const int ch1 = (wv * 2 + 1) * 64 + lane;
  const int xr0 = ch0 >> 5, xr1 = ch1 >> 5;
  const int x0off = xr0 * DX + (((ch0 & 31) ^ (xr0 & 7)) << 2);
  const int x1off = xr1 * DX + (((ch1 & 31) ^ (xr1 & 7)) << 2);
  const int cht = wv * 64 + lane;                      // t: 512 chunks
  const int tr = cht >> 4;
  const int t0off = tr * DT + (((cht & 15) ^ (tr & 7)) << 2);
  const int chy = wv * 64 + lane;                      // y: 256 chunks (wv<4)
  const int yr = chy >> 3;
  const int y0off = yr * MDIM + (((chy & 7) ^ (yr & 7)) << 2);

  const int first = blockIdx.x * TPB;

  auto issue_batch = [&](int tile, int buf) {
    const size_t base = (size_t)tile * TILE_R;
    const float* xb = x + base * DX;
    const float* tb = t + base * DT;
    glds16(xb + x0off, &xs[buf][ch0 * 4]);
    glds16(xb + x1off, &xs[buf][ch1 * 4]);
    glds16(tb + t0off, &ts2[buf][cht * 4]);
    if (wv < 4) glds16(y + base * MDIM + y0off, &ys2[buf][chy * 4]);
  };

  issue_batch(first, 0);   // overlap tile-0 DMA with weight prologue

  // biases, m-major per lane (folded into acc init): m = lhi*4+j (+16)
  const f32x4 bm_lo4 = *(const f32x4*)&bm[wv * MDIM + lhi * 4];
  const f32x4 bm_hi4 = *(const f32x4*)&bm[wv * MDIM + 16 + lhi * 4];
  const f32x4 bv_lo4 = *(const f32x4*)&bv[wv * MDIM + lhi * 4];
  const f32x4 bv_hi4 = *(const f32x4*)&bv[wv * MDIM + 16 + lhi * 4];
  const f32x4 bgv    = *(const f32x4*)&bg[(lhi & 1) * 4];   // k = lhi*4+j (lhi<2)

  // W fragments: lane l15 holds W[d][mcol] for d = lhi*8+i. Used as the
  // A-operand now (A row = l15 = m, k = lhi*8+i) -> D = W^T x^T = mean^T.
  bf16x8 bfrag[4][4];
  #pragma unroll
  for (int ct = 0; ct < 4; ++ct) {
    const float* W = (ct < 2 ? Wm : Wv) + (size_t)wv * (DX * MDIM);
    const int mcol = ((ct & 1) << 4) + l15;
    #pragma unroll
    for (int kk = 0; kk < 4; ++kk) {
      bf16x8 tmp;
      #pragma unroll
      for (int i = 0; i < 8; ++i)
        tmp[i] = (__bf16)W[(kk * 32 + lhi * 8 + i) * MDIM + mcol];
      bfrag[ct][kk] = tmp;
    }
  }
  // Gate weight fragments -> LDS (rows >= KEXP zero-padded)
  #pragma unroll
  for (int kk = 0; kk < 2; ++kk) {
    bf16x8 tmp;
    #pragma unroll
    for (int i = 0; i < 8; ++i) {
      const int d = kk * 32 + lhi * 8 + i;
      tmp[i] = (__bf16)((l15 < KEXP) ? Wg[d * KEXP + l15] : 0.f);
    }
    *(bf16x8*)((char*)wg_lds + (kk * 64 + lane) * 16) = tmp;
  }

  // prologue drain (once): tile-0 DMA + wg_lds writes visible
  asm volatile("s_waitcnt vmcnt(0) lgkmcnt(0)" ::: "memory");
  __builtin_amdgcn_s_barrier();
  __builtin_amdgcn_sched_barrier(0);

  const int grt = wv & 1;        // gate row-half for this wave
  float loss_acc = 0.f;
  const float HL2PI = 0.91893853320467274f;   // 0.5*log(2*pi)

  for (int it = 0; it < TPB; ++it) {
    const int cur = it & 1;

    // issue next-tile DMA (stays in flight across both barriers)
    issue_batch(first + ((it + 1 < TPB) ? it + 1 : it), cur ^ 1);
    // counted wait: all but my new batch retired => tile `it` landed
    if (wv < 4) asm volatile("s_waitcnt vmcnt(4)" ::: "memory");
    else        asm volatile("s_waitcnt vmcnt(3)" ::: "memory");
    __builtin_amdgcn_s_barrier();
    __builtin_amdgcn_sched_barrier(0);

    const float* xc = xs[cur];
    const float* yc = ys2[cur];

    // ---- transposed mean/logvar MFMAs + in-lane Gaussian-LL ----
    #pragma unroll
    for (int rt = 0; rt < 2; ++rt) {
      f32x4 acc0 = bm_lo4, acc1 = bm_hi4, acc2 = bv_lo4, acc3 = bv_hi4;
      const int rbase = (rt * 16 + l15) * DX;
      #pragma unroll
      for (int kk = 0; kk < 4; ++kk) {
        const f32x4 f0 = *(const f32x4*)&xc[rbase + kk * 32 + (((lhi * 2 + 0) ^ swz) << 2)];
        const f32x4 f1 = *(const f32x4*)&xc[rbase + kk * 32 + (((lhi * 2 + 1) ^ swz) << 2)];
        const bf16x8 xf = cvt8(f0, f1);
        acc0 = MFMA16(bfrag[0][kk], xf, acc0);
        acc1 = MFMA16(bfrag[1][kk], xf, acc1);
        acc2 = MFMA16(bfrag[2][kk], xf, acc2);
        acc3 = MFMA16(bfrag[3][kk], xf, acc3);
      }
      // D layout: col = l15 = sample r (this rt-half), row = lhi*4+j = m
      const int r = rt * 16 + l15;
      const f32x4 y0v = *(const f32x4*)&yc[r * MDIM + ((lhi ^ swz) << 2)];
      const f32x4 y1v = *(const f32x4*)&yc[r * MDIM + (((lhi + 4) ^ swz) << 2)];
      float part = 0.f;
      #pragma unroll
      for (int j = 0; j < 4; ++j) {
        const float d0 = y0v[j] - acc0[j];
        const float d1 = y1v[j] - acc1[j];
        part += d0 * d0 * (0.5f * __expf(-acc2[j])) + 0.5f * acc2[j];
        part += d1 * d1 * (0.5f * __expf(-acc3[j])) + 0.5f * acc3[j];
      }
      part += __shfl_xor(part, 16);
      part += __shfl_xor(part, 32);
      if (lhi == 0) ll_s[r * 20 + wv] = -(part + MDIM * HL2PI);
    }

    // ---- transposed gate MFMA (ts2[cur] + wg_lds, BEFORE barrier #2) ----
    // D[k][r]: col = l15 = sample (grt half), row = lhi*4+j = expert k (lhi<2)
    f32x4 lgv;
    {
      const float* tc = ts2[cur];
      const int rb = (grt * 16 + l15) * DT;
      f32x4 g = {0.f, 0.f, 0.f, 0.f};
      #pragma unroll
      for (int kk = 0; kk < 2; ++kk) {
        const f32x4 f0 = *(const f32x4*)&tc[rb + kk * 32 + (((lhi * 2 + 0) ^ swz) << 2)];
        const f32x4 f1 = *(const f32x4*)&tc[rb + kk * 32 + (((lhi * 2 + 1) ^ swz) << 2)];
        const bf16x8 wf = *(const bf16x8*)((const char*)wg_lds + (kk * 64 + lane) * 16);
        g = MFMA16(wf, cvt8(f0, f1), g);
      }
      lgv[0] = g[0] + bgv[0]; lgv[1] = g[1] + bgv[1];
      lgv[2] = g[2] + bgv[2]; lgv[3] = g[3] + bgv[3];
    }

    asm volatile("s_waitcnt lgkmcnt(0)" ::: "memory");
    __builtin_amdgcn_s_barrier();               // #2: ll_s visible
    __builtin_amdgcn_sched_barrier(0);

    // ---- per-sample LSE over experts: in-lane over 4 k's + 1 shfl ----
    {
      const int r = grt * 16 + l15;
      const f32x4 lv4 = *(const f32x4*)&ll_s[r * 20 + lhi * 4];  // lhi>=2: garbage, isolated
      f32x4 a4;
      a4[0] = lgv[0] + lv4[0]; a4[1] = lgv[1] + lv4[1];
      a4[2] = lgv[2] + lv4[2]; a4[3] = lgv[3] + lv4[3];
      float mg = fmaxf(fmaxf(lgv[0], lgv[1]), fmaxf(lgv[2], lgv[3]));
      float ma = fmaxf(fmaxf(a4[0], a4[1]), fmaxf(a4[2], a4[3]));
      mg = fmaxf(mg, __shfl_xor(mg, 16));
      ma = fmaxf(ma, __shfl_xor(ma, 16));
      float eg = __expf(lgv[0] - mg) + __expf(lgv[1] - mg)
               + __expf(lgv[2] - mg) + __expf(lgv[3] - mg);
      float ea = __expf(a4[0] - ma) + __expf(a4[1] - ma)
               + __expf(a4[2] - ma) + __expf(a4[3] - ma);
      eg += __shfl_xor(eg, 16);
      ea += __shfl_xor(ea, 16);
      if (wv < 2 && lhi == 0)
        loss_acc += (mg + __logf(eg)) - (ma + __logf(ea));
    }
  }

  // block reduction of loss
  loss_acc += __shfl_xor(loss_acc, 1);
  loss_acc += __shfl_xor(loss_acc, 2);
  loss_acc += __shfl_xor(loss_acc, 4);
  loss_acc += __shfl_xor(loss_acc, 8);
  loss_acc += __shfl_xor(loss_acc, 16);
  loss_acc += __shfl_xor(loss_acc, 32);
  if (lane == 0) red_s[wv] = loss_acc;
  __syncthreads();
  if (tid == 0) {
    float s = 0.f;
    #pragma unroll
    for (int w = 0; w < 8; ++w) s += red_s[w];
    if (partials) partials[blockIdx.x] = s;
    else atomicAdd(out_atomic, s);
  }
}

__global__ void mdn_reg(const float* __restrict__ Wm, const float* __restrict__ Wv,
                        const float* __restrict__ Wg, float* __restrict__ partials,
                        float* __restrict__ out_atomic)
{
  __shared__ float red[4];
  const int gid = blockIdx.x * 256 + threadIdx.x;
  const int stride = 64 * 256;
  float s = 0.f;
  for (int i = gid; i < DX * MDIM * KEXP; i += stride) { float w = Wm[i]; s += w * w; }
  for (int i = gid; i < DX * MDIM * KEXP; i += stride) { float w = Wv[i]; s += w * w; }
  for (int i = gid; i < DT * KEXP; i += stride)        { float w = Wg[i]; s += w * w; }
  s += __shfl_xor(s, 1);
  s += __shfl_xor(s, 2);
  s += __shfl_xor(s, 4);
  s += __shfl_xor(s, 8);
  s += __shfl_xor(s, 16);
  s += __shfl_xor(s, 32);
  if ((threadIdx.x & 63) == 0) red[threadIdx.x >> 6] = s;
  __syncthreads();
  if (threadIdx.x == 0) {
    float b = red[0] + red[1] + red[2] + red[3];
    if (partials) partials[GRID_MAIN + blockIdx.x] = b;
    else atomicAdd(out_atomic, b);
  }
}

__global__ void mdn_final(const float* __restrict__ partials, float* __restrict__ out)
{
  __shared__ float red[4];
  float s = 0.f;
  for (int i = threadIdx.x; i < GRID_MAIN + 64; i += 256) s += partials[i];
  s += __shfl_xor(s, 1);
  s += __shfl_xor(s, 2);
  s += __shfl_xor(s, 4);
  s += __shfl_xor(s, 8);
  s += __shfl_xor(s, 16);
  s += __shfl_xor(s, 32);
  if ((threadIdx.x & 63) == 0) red[threadIdx.x >> 6] = s;
  __syncthreads();
  if (threadIdx.x == 0) out[0] = red[0] + red[1] + red[2] + red[3];
}

extern "C" void kernel_launch(void* const* d_in, const int* in_sizes, int n_in,
                              void* d_out, int out_size, void* d_ws, size_t ws_size,
                              hipStream_t stream)
{
  const float* x  = (const float*)d_in[0];
  const float* t  = (const float*)d_in[1];
  const float* y  = (const float*)d_in[2];
  const float* Wm = (const float*)d_in[3];
  const float* bm = (const float*)d_in[4];
  const float* Wv = (const float*)d_in[5];
  const float* bv = (const float*)d_in[6];
  const float* Wg = (const float*)d_in[7];
  const float* bg = (const float*)d_in[8];
  float* out = (float*)d_out;

  if (ws_size >= (GRID_MAIN + 64) * sizeof(float)) {
    float* partials = (float*)d_ws;
    mdn_main<<<GRID_MAIN, THREADS, 0, stream>>>(x, t, y, Wm, bm, Wv, bv, Wg, bg,
                                                partials, nullptr);
    mdn_reg<<<64, 256, 0, stream>>>(Wm, Wv, Wg, partials, nullptr);
    mdn_final<<<1, 256, 0, stream>>>(partials, out);
  } else {
    hipMemsetAsync(out, 0, sizeof(float), stream);
    mdn_main<<<GRID_MAIN, THREADS, 0, stream>>>(x, t, y, Wm, bm, Wv, bv, Wg, bg,
                                                nullptr, out);
    mdn_reg<<<64, 256, 0, stream>>>(Wm, Wv, Wg, nullptr, out);
  }
}